// Round 1
// baseline (1770.660 us; speedup 1.0000x reference)
//
#include <hip/hip_runtime.h>
#include <hip/hip_bf16.h>
#include <math.h>

#define N_NODES 100000
#define E_EDGES 3200000
#define K_HOPS  10

// ---------------------------------------------------------------------------
// Tiled fp32 GEMM: C = relu(A(N x KD) @ W(MD x KD)^T + bias), row-major.
// BM=64 rows/block, BK=32, 256 threads, thread tile 4 x TN.
// Safe to call in-place (A == C): each block reads only rows it owns, and all
// reads complete (barrier) before the epilogue stores.
// ---------------------------------------------------------------------------
template<int KD, int MD, int TN>
__global__ __launch_bounds__(256) void mlp_gemm(
    const float* A, const float* __restrict__ W,
    const float* __restrict__ bias, float* C)
{
    constexpr int BM = 64, BK = 32, TM = 4;
    constexpr int CGRP = MD / TN;            // column groups
    static_assert(CGRP * (BM / TM) == 256, "thread mapping");

    __shared__ float As[BK][BM + 4];
    __shared__ float Ws[BK][MD + 4];

    const int t  = threadIdx.x;
    const int cg = t % CGRP;
    const int rg = t / CGRP;
    const int r0 = rg * TM;
    const int c0 = cg * TN;
    const int rowBase = blockIdx.x * BM;

    float acc[TM][TN];
#pragma unroll
    for (int i = 0; i < TM; ++i)
#pragma unroll
        for (int j = 0; j < TN; ++j) acc[i][j] = 0.f;

    for (int kt = 0; kt < KD; kt += BK) {
        // stage A tile (BM x BK), transposed into As[k][m]
#pragma unroll
        for (int i = t; i < BM * BK / 4; i += 256) {
            int row = i / (BK / 4);
            int c4  = (i % (BK / 4)) * 4;
            int gr  = rowBase + row;
            float4 v = make_float4(0.f, 0.f, 0.f, 0.f);
            if (gr < N_NODES) v = *(const float4*)&A[(size_t)gr * KD + kt + c4];
            As[c4 + 0][row] = v.x; As[c4 + 1][row] = v.y;
            As[c4 + 2][row] = v.z; As[c4 + 3][row] = v.w;
        }
        // stage W tile (MD x BK), transposed into Ws[k][n]
#pragma unroll
        for (int i = t; i < MD * BK / 4; i += 256) {
            int nn = i / (BK / 4);
            int c4 = (i % (BK / 4)) * 4;
            float4 v = *(const float4*)&W[(size_t)nn * KD + kt + c4];
            Ws[c4 + 0][nn] = v.x; Ws[c4 + 1][nn] = v.y;
            Ws[c4 + 2][nn] = v.z; Ws[c4 + 3][nn] = v.w;
        }
        __syncthreads();
#pragma unroll
        for (int k = 0; k < BK; ++k) {
            float4 av = *(const float4*)&As[k][r0];
            float a[TM] = {av.x, av.y, av.z, av.w};
            float b[TN];
#pragma unroll
            for (int j = 0; j < TN; ++j) b[j] = Ws[k][c0 + j];
#pragma unroll
            for (int i = 0; i < TM; ++i)
#pragma unroll
                for (int j = 0; j < TN; ++j) acc[i][j] += a[i] * b[j];
        }
        __syncthreads();
    }

    // epilogue: bias + relu
#pragma unroll
    for (int i = 0; i < TM; ++i) {
        int gr = rowBase + r0 + i;
        if (gr < N_NODES) {
#pragma unroll
            for (int j = 0; j < TN; ++j) {
                float v = acc[i][j] + bias[c0 + j];
                C[(size_t)gr * MD + c0 + j] = v > 0.f ? v : 0.f;
            }
        }
    }
}

// ---------------------------------------------------------------------------
// CSR build: histogram of dst -> exclusive scan -> cursor fill
// ---------------------------------------------------------------------------
__global__ void hist_kernel(const int* __restrict__ dst, int* __restrict__ cnt)
{
    int i = blockIdx.x * blockDim.x + threadIdx.x;
    if (i < E_EDGES) atomicAdd(&cnt[dst[i]], 1);
}

__global__ __launch_bounds__(1024) void scan_kernel(
    const int* __restrict__ cnt, int* __restrict__ row_ptr, int* __restrict__ cursor)
{
    __shared__ int swave[16];
    __shared__ int sbro[17];
    const int t = threadIdx.x, lane = t & 63, wid = t >> 6;
    int running = 0;
    for (int base = 0; base < N_NODES; base += 1024) {
        int i = base + t;
        int v = (i < N_NODES) ? cnt[i] : 0;
        int x = v;
#pragma unroll
        for (int d = 1; d < 64; d <<= 1) {
            int y = __shfl_up(x, d);
            if (lane >= d) x += y;
        }
        if (lane == 63) swave[wid] = x;
        __syncthreads();
        if (wid == 0) {
            int s = (lane < 16) ? swave[lane] : 0;
#pragma unroll
            for (int d = 1; d < 16; d <<= 1) {
                int y = __shfl_up(s, d);
                if (lane >= d) s += y;
            }
            if (lane < 16) sbro[lane + 1] = s;
            if (lane == 0) sbro[0] = 0;
        }
        __syncthreads();
        int inc  = x + sbro[wid] + running;   // inclusive prefix overall
        int excl = inc - v;
        if (i < N_NODES) { row_ptr[i] = excl; cursor[i] = excl; }
        running += sbro[16];
        __syncthreads();                      // protect swave/sbro reuse
    }
    if (t == 0) row_ptr[N_NODES] = running;
}

__global__ void fill_kernel(const int* __restrict__ src, const int* __restrict__ dst,
                            const float* __restrict__ ea, int* __restrict__ cursor,
                            int* __restrict__ csr_src, float* __restrict__ csr_norm)
{
    int i = blockIdx.x * blockDim.x + threadIdx.x;
    if (i < E_EDGES) {
        int d = dst[i];
        int p = atomicAdd(&cursor[d], 1);
        csr_src[p]  = src[i];
        csr_norm[p] = ea[i];
    }
}

// ---------------------------------------------------------------------------
// out = sigmoid(h . pw + pb) * h   (k=0 term; initializes out)
// 4 lanes per node, float4 per lane.
// ---------------------------------------------------------------------------
__global__ __launch_bounds__(256) void init_out_kernel(
    const float* __restrict__ h, const float* __restrict__ proj_w,
    const float* __restrict__ proj_b, float* __restrict__ out)
{
    const int t = threadIdx.x;
    const int l = t & 3;
    const int n = blockIdx.x * 64 + (t >> 2);
    if (n >= N_NODES) return;
    float4 v  = *(const float4*)&h[(size_t)n * 16 + l * 4];
    float4 pw = ((const float4*)proj_w)[l];
    float part = v.x * pw.x + v.y * pw.y + v.z * pw.z + v.w * pw.w;
    part += __shfl_xor(part, 1);
    part += __shfl_xor(part, 2);
    float s = 1.f / (1.f + __expf(-(part + proj_b[0])));
    float4 o = make_float4(s * v.x, s * v.y, s * v.z, s * v.w);
    *(float4*)&out[(size_t)n * 16 + l * 4] = o;
}

// ---------------------------------------------------------------------------
// One hop: next[n] = sum_{e in CSR row n} norm_e * prev[src_e]
// plus fused DAGNN accumulate: out[n] += sigmoid(next[n].pw + pb) * next[n]
// ---------------------------------------------------------------------------
__global__ __launch_bounds__(256) void hop_kernel(
    const float* __restrict__ prev, float* __restrict__ next,
    const int* __restrict__ row_ptr, const int* __restrict__ csr_src,
    const float* __restrict__ csr_norm,
    const float* __restrict__ proj_w, const float* __restrict__ proj_b,
    float* __restrict__ out)
{
    const int t = threadIdx.x;
    const int l = t & 3;
    const int n = blockIdx.x * 64 + (t >> 2);
    if (n >= N_NODES) return;
    const int e0 = row_ptr[n], e1 = row_ptr[n + 1];
    float4 acc = make_float4(0.f, 0.f, 0.f, 0.f);
    for (int e = e0; e < e1; ++e) {
        int   s = csr_src[e];
        float w = csr_norm[e];
        float4 v = *(const float4*)&prev[(size_t)s * 16 + l * 4];
        acc.x += w * v.x; acc.y += w * v.y; acc.z += w * v.z; acc.w += w * v.w;
    }
    *(float4*)&next[(size_t)n * 16 + l * 4] = acc;

    float4 pw = ((const float4*)proj_w)[l];
    float part = acc.x * pw.x + acc.y * pw.y + acc.z * pw.z + acc.w * pw.w;
    part += __shfl_xor(part, 1);
    part += __shfl_xor(part, 2);
    float s = 1.f / (1.f + __expf(-(part + proj_b[0])));
    float4 o = *(float4*)&out[(size_t)n * 16 + l * 4];
    o.x += s * acc.x; o.y += s * acc.y; o.z += s * acc.z; o.w += s * acc.w;
    *(float4*)&out[(size_t)n * 16 + l * 4] = o;
}

// ---------------------------------------------------------------------------
extern "C" void kernel_launch(void* const* d_in, const int* in_sizes, int n_in,
                              void* d_out, int out_size, void* d_ws, size_t ws_size,
                              hipStream_t stream)
{
    const float* x  = (const float*)d_in[0];
    const int*   ei = (const int*)d_in[1];
    const float* ea = (const float*)d_in[2];
    const float* w1 = (const float*)d_in[3];
    const float* b1 = (const float*)d_in[4];
    const float* w2 = (const float*)d_in[5];
    const float* b2 = (const float*)d_in[6];
    const float* w3 = (const float*)d_in[7];
    const float* b3 = (const float*)d_in[8];
    const float* pw = (const float*)d_in[9];
    const float* pb = (const float*)d_in[10];
    float* out = (float*)d_out;

    char* ws = (char*)d_ws;
    size_t off = 0;
    float* hbuf = (float*)(ws + off); off += (size_t)N_NODES * 128 * 4;   // 51.2 MB
    float* ping = (float*)(ws + off); off += (size_t)N_NODES * 16 * 4;    // 6.4 MB
    float* pong = (float*)(ws + off); off += (size_t)N_NODES * 16 * 4;    // 6.4 MB
    int*   cnt  = (int*)(ws + off);   off += (((size_t)(N_NODES + 1) * 4) + 15) & ~(size_t)15;
    int*   rowp = (int*)(ws + off);   off += (((size_t)(N_NODES + 1) * 4) + 15) & ~(size_t)15;
    int*   curs = (int*)(ws + off);   off += (((size_t)(N_NODES + 1) * 4) + 15) & ~(size_t)15;
    int*   csrc = (int*)(ws + off);   off += (size_t)E_EDGES * 4;
    float* cnrm = (float*)(ws + off); off += (size_t)E_EDGES * 4;
    // total ~90.8 MB of ws

    const int* src = ei;
    const int* dst = ei + E_EDGES;

    const dim3 blk(256);
    const int nodeGrid = (N_NODES + 63) / 64;
    const int edgeGrid = (E_EDGES + 255) / 256;

    // CSR build (dst-major)
    hipMemsetAsync(cnt, 0, (size_t)(N_NODES + 1) * 4, stream);
    hist_kernel<<<edgeGrid, blk, 0, stream>>>(dst, cnt);
    scan_kernel<<<1, 1024, 0, stream>>>(cnt, rowp, curs);
    fill_kernel<<<edgeGrid, blk, 0, stream>>>(src, dst, ea, curs, csrc, cnrm);

    // MLP
    mlp_gemm<256, 128, 8><<<nodeGrid, blk, 0, stream>>>(x, w1, b1, hbuf);
    mlp_gemm<128, 128, 8><<<nodeGrid, blk, 0, stream>>>(hbuf, w2, b2, hbuf); // in-place
    mlp_gemm<128, 16, 1><<<nodeGrid, blk, 0, stream>>>(hbuf, w3, b3, ping);

    // k=0 term
    init_out_kernel<<<nodeGrid, blk, 0, stream>>>(ping, pw, pb, out);

    // K hops with fused combine
    const float* prev = ping;
    float* next = pong;
    for (int k = 0; k < K_HOPS; ++k) {
        hop_kernel<<<nodeGrid, blk, 0, stream>>>(prev, next, rowp, csrc, cnrm, pw, pb, out);
        float* tmp = (float*)prev; prev = next; next = tmp;
    }
}

// Round 2
// 1381.408 us; speedup vs baseline: 1.2818x; 1.2818x over previous
//
#include <hip/hip_runtime.h>
#include <hip/hip_bf16.h>
#include <math.h>

#define N_NODES 100000
#define E_EDGES 3200000
#define K_HOPS  10
#define NB_BUCKETS ((N_NODES + 63) / 64)   // 1563 buckets of 64 nodes

// ---------------------------------------------------------------------------
// Tiled fp32 GEMM: C = relu(A(N x KD) @ W(MD x KD)^T + bias), row-major.
// BM=64 rows/block, BK=32, 256 threads, thread tile 4 x TN.
// Safe in-place (A == C): blocks read only rows they own; reads complete
// (barrier) before epilogue stores.
// ---------------------------------------------------------------------------
template<int KD, int MD, int TN>
__global__ __launch_bounds__(256) void mlp_gemm(
    const float* A, const float* __restrict__ W,
    const float* __restrict__ bias, float* C)
{
    constexpr int BM = 64, BK = 32, TM = 4;
    constexpr int CGRP = MD / TN;
    static_assert(CGRP * (BM / TM) == 256, "thread mapping");

    __shared__ float As[BK][BM + 4];
    __shared__ float Ws[BK][MD + 4];

    const int t  = threadIdx.x;
    const int cg = t % CGRP;
    const int rg = t / CGRP;
    const int r0 = rg * TM;
    const int c0 = cg * TN;
    const int rowBase = blockIdx.x * BM;

    float acc[TM][TN];
#pragma unroll
    for (int i = 0; i < TM; ++i)
#pragma unroll
        for (int j = 0; j < TN; ++j) acc[i][j] = 0.f;

    for (int kt = 0; kt < KD; kt += BK) {
#pragma unroll
        for (int i = t; i < BM * BK / 4; i += 256) {
            int row = i / (BK / 4);
            int c4  = (i % (BK / 4)) * 4;
            int gr  = rowBase + row;
            float4 v = make_float4(0.f, 0.f, 0.f, 0.f);
            if (gr < N_NODES) v = *(const float4*)&A[(size_t)gr * KD + kt + c4];
            As[c4 + 0][row] = v.x; As[c4 + 1][row] = v.y;
            As[c4 + 2][row] = v.z; As[c4 + 3][row] = v.w;
        }
#pragma unroll
        for (int i = t; i < MD * BK / 4; i += 256) {
            int nn = i / (BK / 4);
            int c4 = (i % (BK / 4)) * 4;
            float4 v = *(const float4*)&W[(size_t)nn * KD + kt + c4];
            Ws[c4 + 0][nn] = v.x; Ws[c4 + 1][nn] = v.y;
            Ws[c4 + 2][nn] = v.z; Ws[c4 + 3][nn] = v.w;
        }
        __syncthreads();
#pragma unroll
        for (int k = 0; k < BK; ++k) {
            float4 av = *(const float4*)&As[k][r0];
            float a[TM] = {av.x, av.y, av.z, av.w};
            float b[TN];
#pragma unroll
            for (int j = 0; j < TN; ++j) b[j] = Ws[k][c0 + j];
#pragma unroll
            for (int i = 0; i < TM; ++i)
#pragma unroll
                for (int j = 0; j < TN; ++j) acc[i][j] += a[i] * b[j];
        }
        __syncthreads();
    }

#pragma unroll
    for (int i = 0; i < TM; ++i) {
        int gr = rowBase + r0 + i;
        if (gr < N_NODES) {
#pragma unroll
            for (int j = 0; j < TN; ++j) {
                float v = acc[i][j] + bias[c0 + j];
                C[(size_t)gr * MD + c0 + j] = v > 0.f ? v : 0.f;
            }
        }
    }
}

// ---------------------------------------------------------------------------
// CSR build, stage 1: histogram of dst
// ---------------------------------------------------------------------------
__global__ void hist_kernel(const int* __restrict__ dst, int* __restrict__ cnt)
{
    int i = blockIdx.x * blockDim.x + threadIdx.x;
    if (i < E_EDGES) atomicAdd(&cnt[dst[i]], 1);
}

// ---------------------------------------------------------------------------
// Stage 2: single-block exclusive scan, 4 elements per thread (int4).
// ---------------------------------------------------------------------------
__global__ __launch_bounds__(1024) void scan_kernel(
    const int* __restrict__ cnt, int* __restrict__ row_ptr)
{
    __shared__ int swave[16];
    __shared__ int sbro[17];
    const int t = threadIdx.x, lane = t & 63, wid = t >> 6;
    int running = 0;
    for (int base = 0; base < N_NODES; base += 4096) {
        int i = base + t * 4;
        int4 v = make_int4(0, 0, 0, 0);
        if (i + 3 < N_NODES) v = *(const int4*)&cnt[i];
        else {
            if (i     < N_NODES) v.x = cnt[i];
            if (i + 1 < N_NODES) v.y = cnt[i + 1];
            if (i + 2 < N_NODES) v.z = cnt[i + 2];
            if (i + 3 < N_NODES) v.w = cnt[i + 3];
        }
        int s1 = v.x, s2 = s1 + v.y, s3 = s2 + v.z, s4 = s3 + v.w;
        int x = s4;
#pragma unroll
        for (int d = 1; d < 64; d <<= 1) {
            int y = __shfl_up(x, d);
            if (lane >= d) x += y;
        }
        if (lane == 63) swave[wid] = x;
        __syncthreads();
        if (wid == 0) {
            int s = (lane < 16) ? swave[lane] : 0;
#pragma unroll
            for (int d = 1; d < 16; d <<= 1) {
                int y = __shfl_up(s, d);
                if (lane >= d) s += y;
            }
            if (lane < 16) sbro[lane + 1] = s;
            if (lane == 0) sbro[0] = 0;
        }
        __syncthreads();
        int pre = running + sbro[wid] + (x - s4);   // exclusive prefix
        if (i     < N_NODES) row_ptr[i]     = pre;
        if (i + 1 < N_NODES) row_ptr[i + 1] = pre + s1;
        if (i + 2 < N_NODES) row_ptr[i + 2] = pre + s2;
        if (i + 3 < N_NODES) row_ptr[i + 3] = pre + s3;
        running += sbro[16];
        __syncthreads();
    }
    if (t == 0) row_ptr[N_NODES] = running;
}

// ---------------------------------------------------------------------------
// Stage 3a: per-bucket cursor init (bucket b = nodes [b*64, b*64+64))
// ---------------------------------------------------------------------------
__global__ void init_bcur(const int* __restrict__ rowp, int* __restrict__ bcur)
{
    int b = blockIdx.x * blockDim.x + threadIdx.x;
    if (b < NB_BUCKETS) bcur[b] = rowp[b * 64];
}

// ---------------------------------------------------------------------------
// Stage 3b: scatter edges into bucket regions of staging (16B packed entries).
// Writes are confined to 1563 live regions -> L2-friendly.
// ---------------------------------------------------------------------------
__global__ void bucket_scatter(const int* __restrict__ src, const int* __restrict__ dst,
                               const float* __restrict__ ea, int* __restrict__ bcur,
                               int4* __restrict__ staging)
{
    int i = blockIdx.x * blockDim.x + threadIdx.x;
    if (i < E_EDGES) {
        int d = dst[i];
        int b = d >> 6;
        int p = atomicAdd(&bcur[b], 1);
        staging[p] = make_int4(src[i], __float_as_int(ea[i]), d, 0);
    }
}

// ---------------------------------------------------------------------------
// Stage 4: one block per bucket; reorder staging -> final packed CSR using
// LDS cursors. All stores land in a ~16KB contiguous region per block.
// ---------------------------------------------------------------------------
__global__ __launch_bounds__(256) void bucket_to_csr(
    const int4* __restrict__ staging, const int* __restrict__ rowp,
    int2* __restrict__ csr)
{
    __shared__ int lcur[64];
    const int b = blockIdx.x;
    const int nbase = b * 64;
    const int t = threadIdx.x;
    if (t < 64) {
        int n = nbase + t;
        lcur[t] = (n < N_NODES) ? rowp[n] : 0;
    }
    __syncthreads();
    const int nend = (nbase + 64 < N_NODES) ? nbase + 64 : N_NODES;
    const int e0 = rowp[nbase];
    const int e1 = rowp[nend];
    for (int e = e0 + t; e < e1; e += 256) {
        int4 en = staging[e];
        int p = atomicAdd(&lcur[en.z - nbase], 1);
        csr[p] = make_int2(en.x, en.y);
    }
}

// ---------------------------------------------------------------------------
// out = sigmoid(h . pw + pb) * h   (k=0 term; initializes out)
// ---------------------------------------------------------------------------
__global__ __launch_bounds__(256) void init_out_kernel(
    const float* __restrict__ h, const float* __restrict__ proj_w,
    const float* __restrict__ proj_b, float* __restrict__ out)
{
    const int t = threadIdx.x;
    const int l = t & 3;
    const int n = blockIdx.x * 64 + (t >> 2);
    if (n >= N_NODES) return;
    float4 v  = *(const float4*)&h[(size_t)n * 16 + l * 4];
    float4 pw = ((const float4*)proj_w)[l];
    float part = v.x * pw.x + v.y * pw.y + v.z * pw.z + v.w * pw.w;
    part += __shfl_xor(part, 1);
    part += __shfl_xor(part, 2);
    float s = 1.f / (1.f + __expf(-(part + proj_b[0])));
    *(float4*)&out[(size_t)n * 16 + l * 4] =
        make_float4(s * v.x, s * v.y, s * v.z, s * v.w);
}

// ---------------------------------------------------------------------------
// One hop + fused DAGNN combine. 16 lanes per node:
//   l = feature chunk (4 x float4), g = edge subgroup (4-way MLP),
// manual 2x unroll -> up to 8 gathers in flight per node.
// ---------------------------------------------------------------------------
__global__ __launch_bounds__(256) void hop_kernel(
    const float* __restrict__ prev, float* __restrict__ next,
    const int* __restrict__ row_ptr, const int2* __restrict__ csr,
    const float* __restrict__ proj_w, const float* __restrict__ proj_b,
    float* __restrict__ out)
{
    const int t = threadIdx.x;
    const int l = t & 3;
    const int g = (t >> 2) & 3;
    const int n = blockIdx.x * 16 + (t >> 4);
    if (n >= N_NODES) return;
    const int e0 = row_ptr[n], e1 = row_ptr[n + 1];
    float4 acc = make_float4(0.f, 0.f, 0.f, 0.f);
    int e = e0 + g;
    for (; e + 4 < e1; e += 8) {
        int2 ea = csr[e];
        int2 eb = csr[e + 4];
        float  wa = __int_as_float(ea.y);
        float  wb = __int_as_float(eb.y);
        float4 va = *(const float4*)&prev[(size_t)ea.x * 16 + l * 4];
        float4 vb = *(const float4*)&prev[(size_t)eb.x * 16 + l * 4];
        acc.x += wa * va.x; acc.y += wa * va.y; acc.z += wa * va.z; acc.w += wa * va.w;
        acc.x += wb * vb.x; acc.y += wb * vb.y; acc.z += wb * vb.z; acc.w += wb * vb.w;
    }
    if (e < e1) {
        int2 ea = csr[e];
        float  wa = __int_as_float(ea.y);
        float4 va = *(const float4*)&prev[(size_t)ea.x * 16 + l * 4];
        acc.x += wa * va.x; acc.y += wa * va.y; acc.z += wa * va.z; acc.w += wa * va.w;
    }
    // reduce over edge subgroups (xor 4, 8)
    acc.x += __shfl_xor(acc.x, 4); acc.y += __shfl_xor(acc.y, 4);
    acc.z += __shfl_xor(acc.z, 4); acc.w += __shfl_xor(acc.w, 4);
    acc.x += __shfl_xor(acc.x, 8); acc.y += __shfl_xor(acc.y, 8);
    acc.z += __shfl_xor(acc.z, 8); acc.w += __shfl_xor(acc.w, 8);

    float4 pw = ((const float4*)proj_w)[l];
    float part = acc.x * pw.x + acc.y * pw.y + acc.z * pw.z + acc.w * pw.w;
    part += __shfl_xor(part, 1);
    part += __shfl_xor(part, 2);
    float s = 1.f / (1.f + __expf(-(part + proj_b[0])));

    if (g == 0) {
        *(float4*)&next[(size_t)n * 16 + l * 4] = acc;
        float4 o = *(float4*)&out[(size_t)n * 16 + l * 4];
        o.x += s * acc.x; o.y += s * acc.y; o.z += s * acc.z; o.w += s * acc.w;
        *(float4*)&out[(size_t)n * 16 + l * 4] = o;
    }
}

// ---------------------------------------------------------------------------
extern "C" void kernel_launch(void* const* d_in, const int* in_sizes, int n_in,
                              void* d_out, int out_size, void* d_ws, size_t ws_size,
                              hipStream_t stream)
{
    const float* x  = (const float*)d_in[0];
    const int*   ei = (const int*)d_in[1];
    const float* ea = (const float*)d_in[2];
    const float* w1 = (const float*)d_in[3];
    const float* b1 = (const float*)d_in[4];
    const float* w2 = (const float*)d_in[5];
    const float* b2 = (const float*)d_in[6];
    const float* w3 = (const float*)d_in[7];
    const float* b3 = (const float*)d_in[8];
    const float* pw = (const float*)d_in[9];
    const float* pb = (const float*)d_in[10];
    float* out = (float*)d_out;

    char* ws = (char*)d_ws;
    size_t off = 0;
    float* hbuf = (float*)(ws + off); off += (size_t)N_NODES * 128 * 4;   // 51.2 MB
    float* ping = (float*)(ws + off); off += (size_t)N_NODES * 16 * 4;    // 6.4 MB
    float* pong = (float*)(ws + off); off += (size_t)N_NODES * 16 * 4;    // 6.4 MB
    int*   cnt  = (int*)(ws + off);   off += (((size_t)(N_NODES + 1) * 4) + 15) & ~(size_t)15;
    int*   rowp = (int*)(ws + off);   off += (((size_t)(N_NODES + 1) * 4) + 15) & ~(size_t)15;
    int*   bcur = (int*)(ws + off);   off += ((size_t)NB_BUCKETS * 4 + 15) & ~(size_t)15;
    int2*  csr  = (int2*)(ws + off);  off += (size_t)E_EDGES * 8;
    // staging (3.2M x 16B = 51.2MB) aliases hbuf: CSR build completes
    // (stream-ordered) before mlp1 writes hbuf.
    int4* staging = (int4*)hbuf;

    const int* src = ei;
    const int* dst = ei + E_EDGES;

    const dim3 blk(256);
    const int nodeGrid16 = (N_NODES + 15) / 16;
    const int nodeGrid64 = (N_NODES + 63) / 64;
    const int edgeGrid   = (E_EDGES + 255) / 256;

    // ---- CSR build (dst-major), bucketed two-pass ----
    hipMemsetAsync(cnt, 0, (size_t)(N_NODES + 1) * 4, stream);
    hist_kernel<<<edgeGrid, blk, 0, stream>>>(dst, cnt);
    scan_kernel<<<1, 1024, 0, stream>>>(cnt, rowp);
    init_bcur<<<(NB_BUCKETS + 255) / 256, blk, 0, stream>>>(rowp, bcur);
    bucket_scatter<<<edgeGrid, blk, 0, stream>>>(src, dst, ea, bcur, staging);
    bucket_to_csr<<<NB_BUCKETS, blk, 0, stream>>>(staging, rowp, csr);

    // ---- MLP (overwrites staging/hbuf after CSR build is done) ----
    mlp_gemm<256, 128, 8><<<nodeGrid64, blk, 0, stream>>>(x, w1, b1, hbuf);
    mlp_gemm<128, 128, 8><<<nodeGrid64, blk, 0, stream>>>(hbuf, w2, b2, hbuf);
    mlp_gemm<128, 16, 1><<<nodeGrid64, blk, 0, stream>>>(hbuf, w3, b3, ping);

    // ---- k=0 combine term ----
    init_out_kernel<<<nodeGrid64, blk, 0, stream>>>(ping, pw, pb, out);

    // ---- K hops with fused combine ----
    const float* prev = ping;
    float* next = pong;
    for (int k = 0; k < K_HOPS; ++k) {
        hop_kernel<<<nodeGrid16, blk, 0, stream>>>(prev, next, rowp, csr, pw, pb, out);
        float* tmp = (float*)prev; prev = next; next = tmp;
    }
}

// Round 3
// 879.226 us; speedup vs baseline: 2.0139x; 1.5712x over previous
//
#include <hip/hip_runtime.h>
#include <hip/hip_bf16.h>
#include <math.h>

#define N_NODES 100000
#define E_EDGES 3200000
#define K_HOPS  10
#define NPP     512                         // nodes per partition (dst>>9)
#define NPART   ((N_NODES + NPP - 1) / NPP) // 196 partitions
#define CHUNK   8192                        // edges per scatter block
#define EPT     (CHUNK / 256)               // 32 edges per thread

// ---------------------------------------------------------------------------
// Tiled fp32 GEMM: C = relu(A(N x KD) @ W(MD x KD)^T + bias), row-major.
// Safe in-place (A == C).
// ---------------------------------------------------------------------------
template<int KD, int MD, int TN>
__global__ __launch_bounds__(256) void mlp_gemm(
    const float* A, const float* __restrict__ W,
    const float* __restrict__ bias, float* C)
{
    constexpr int BM = 64, BK = 32, TM = 4;
    constexpr int CGRP = MD / TN;
    static_assert(CGRP * (BM / TM) == 256, "thread mapping");

    __shared__ float As[BK][BM + 4];
    __shared__ float Ws[BK][MD + 4];

    const int t  = threadIdx.x;
    const int cg = t % CGRP;
    const int rg = t / CGRP;
    const int r0 = rg * TM;
    const int c0 = cg * TN;
    const int rowBase = blockIdx.x * BM;

    float acc[TM][TN];
#pragma unroll
    for (int i = 0; i < TM; ++i)
#pragma unroll
        for (int j = 0; j < TN; ++j) acc[i][j] = 0.f;

    for (int kt = 0; kt < KD; kt += BK) {
#pragma unroll
        for (int i = t; i < BM * BK / 4; i += 256) {
            int row = i / (BK / 4);
            int c4  = (i % (BK / 4)) * 4;
            int gr  = rowBase + row;
            float4 v = make_float4(0.f, 0.f, 0.f, 0.f);
            if (gr < N_NODES) v = *(const float4*)&A[(size_t)gr * KD + kt + c4];
            As[c4 + 0][row] = v.x; As[c4 + 1][row] = v.y;
            As[c4 + 2][row] = v.z; As[c4 + 3][row] = v.w;
        }
#pragma unroll
        for (int i = t; i < MD * BK / 4; i += 256) {
            int nn = i / (BK / 4);
            int c4 = (i % (BK / 4)) * 4;
            float4 v = *(const float4*)&W[(size_t)nn * KD + kt + c4];
            Ws[c4 + 0][nn] = v.x; Ws[c4 + 1][nn] = v.y;
            Ws[c4 + 2][nn] = v.z; Ws[c4 + 3][nn] = v.w;
        }
        __syncthreads();
#pragma unroll
        for (int k = 0; k < BK; ++k) {
            float4 av = *(const float4*)&As[k][r0];
            float a[TM] = {av.x, av.y, av.z, av.w};
            float b[TN];
#pragma unroll
            for (int j = 0; j < TN; ++j) b[j] = Ws[k][c0 + j];
#pragma unroll
            for (int i = 0; i < TM; ++i)
#pragma unroll
                for (int j = 0; j < TN; ++j) acc[i][j] += a[i] * b[j];
        }
        __syncthreads();
    }

#pragma unroll
    for (int i = 0; i < TM; ++i) {
        int gr = rowBase + r0 + i;
        if (gr < N_NODES) {
#pragma unroll
            for (int j = 0; j < TN; ++j) {
                float v = acc[i][j] + bias[c0 + j];
                C[(size_t)gr * MD + c0 + j] = v > 0.f ? v : 0.f;
            }
        }
    }
}

// ---------------------------------------------------------------------------
// CSR build stage A: per-partition histogram (LDS) -> global pcnt
// ---------------------------------------------------------------------------
__global__ __launch_bounds__(256) void partition_hist(
    const int* __restrict__ dst, int* __restrict__ pcnt)
{
    __shared__ int lhist[256];
    const int t = threadIdx.x;
    lhist[t] = 0;
    __syncthreads();
    const int base = blockIdx.x * CHUNK;
#pragma unroll
    for (int j = 0; j < EPT; ++j) {
        int i = base + j * 256 + t;
        if (i < E_EDGES) atomicAdd(&lhist[dst[i] >> 9], 1);
    }
    __syncthreads();
    if (lhist[t] > 0) atomicAdd(&pcnt[t], lhist[t]);
}

// ---------------------------------------------------------------------------
// Stage B: exclusive scan of 196 partition counts (1 block, Hillis-Steele)
// ---------------------------------------------------------------------------
__global__ __launch_bounds__(256) void partition_scan(
    const int* __restrict__ pcnt, int* __restrict__ pbase, int* __restrict__ pcur)
{
    __shared__ int buf[2][256];
    const int t = threadIdx.x;
    int v = (t < NPART) ? pcnt[t] : 0;
    buf[0][t] = v;
    __syncthreads();
    int cur = 0;
#pragma unroll
    for (int d = 1; d < 256; d <<= 1) {
        int x = buf[cur][t];
        if (t >= d) x += buf[cur][t - d];
        buf[cur ^ 1][t] = x;
        cur ^= 1;
        __syncthreads();
    }
    int incl = buf[cur][t];
    int excl = incl - v;
    if (t < NPART) { pbase[t] = excl; pcur[t] = excl; }
    if (t == NPART - 1) pbase[NPART] = incl;
}

// ---------------------------------------------------------------------------
// Stage C: multi-split scatter into partition-major staging (16B entries).
// One global atomic per (block, partition); writes are contiguous bursts.
// ---------------------------------------------------------------------------
__global__ __launch_bounds__(256) void partition_scatter(
    const int* __restrict__ src, const int* __restrict__ dst,
    const float* __restrict__ ea, int* __restrict__ pcur,
    int4* __restrict__ staging)
{
    __shared__ int lhist[256];
    __shared__ int lbase[256];
    const int t = threadIdx.x;
    lhist[t] = 0;
    __syncthreads();
    const int base = blockIdx.x * CHUNK;
    int d[EPT];
#pragma unroll
    for (int j = 0; j < EPT; ++j) {
        int i = base + j * 256 + t;
        d[j] = (i < E_EDGES) ? dst[i] : -1;
        if (d[j] >= 0) atomicAdd(&lhist[d[j] >> 9], 1);
    }
    __syncthreads();
    int cnt = lhist[t];
    if (cnt > 0) lbase[t] = atomicAdd(&pcur[t], cnt);
    __syncthreads();
    lhist[t] = 0;
    __syncthreads();
#pragma unroll
    for (int j = 0; j < EPT; ++j) {
        if (d[j] >= 0) {
            int i = base + j * 256 + t;
            int p = d[j] >> 9;
            int r = atomicAdd(&lhist[p], 1);
            staging[lbase[p] + r] = make_int4(src[i], __float_as_int(ea[i]), d[j], 0);
        }
    }
}

// ---------------------------------------------------------------------------
// Stage D: one block per partition. LDS per-node hist + scan -> rowp, then
// scatter staged edges to final packed CSR. All stores land in a ~130KB
// window per block (L2-resident).
// ---------------------------------------------------------------------------
__global__ __launch_bounds__(256) void partition_build(
    const int4* __restrict__ staging, const int* __restrict__ pbase,
    int* __restrict__ rowp, int2* __restrict__ csr)
{
    __shared__ int ncnt[NPP];   // counts, then reused as absolute cursors
    __shared__ int wsum[4];
    const int p = blockIdx.x;
    const int t = threadIdx.x;
    const int lane = t & 63, wid = t >> 6;
    const int e0 = pbase[p], e1 = pbase[p + 1];
    const int n0 = p * NPP;

    ncnt[2 * t] = 0; ncnt[2 * t + 1] = 0;
    __syncthreads();
    for (int e = e0 + t; e < e1; e += 256)
        atomicAdd(&ncnt[staging[e].z - n0], 1);
    __syncthreads();

    // exclusive scan of 512 counts (2 per thread)
    int a = ncnt[2 * t], b = ncnt[2 * t + 1];
    int pairsum = a + b;
    int x = pairsum;
#pragma unroll
    for (int dd = 1; dd < 64; dd <<= 1) {
        int y = __shfl_up(x, dd);
        if (lane >= dd) x += y;
    }
    if (lane == 63) wsum[wid] = x;
    __syncthreads();
    int wbase = 0;
    for (int w = 0; w < 4; ++w) if (w < wid) wbase += wsum[w];
    int excl = wbase + x - pairsum;          // exclusive over 512
    __syncthreads();
    ncnt[2 * t]     = e0 + excl;             // absolute cursor
    ncnt[2 * t + 1] = e0 + excl + a;
    int nA = n0 + 2 * t, nB = n0 + 2 * t + 1;
    if (nA < N_NODES) rowp[nA] = e0 + excl;
    if (nB < N_NODES) rowp[nB] = e0 + excl + a;
    if (p == NPART - 1 && t == 0) rowp[N_NODES] = E_EDGES;
    __syncthreads();

    for (int e = e0 + t; e < e1; e += 256) {
        int4 en = staging[e];
        int pos = atomicAdd(&ncnt[en.z - n0], 1);
        csr[pos] = make_int2(en.x, en.y);
    }
}

// ---------------------------------------------------------------------------
// out = sigmoid(h . pw + pb) * h   (k=0 term; initializes out)
// ---------------------------------------------------------------------------
__global__ __launch_bounds__(256) void init_out_kernel(
    const float* __restrict__ h, const float* __restrict__ proj_w,
    const float* __restrict__ proj_b, float* __restrict__ out)
{
    const int t = threadIdx.x;
    const int l = t & 3;
    const int n = blockIdx.x * 64 + (t >> 2);
    if (n >= N_NODES) return;
    float4 v  = *(const float4*)&h[(size_t)n * 16 + l * 4];
    float4 pw = ((const float4*)proj_w)[l];
    float part = v.x * pw.x + v.y * pw.y + v.z * pw.z + v.w * pw.w;
    part += __shfl_xor(part, 1);
    part += __shfl_xor(part, 2);
    float s = 1.f / (1.f + __expf(-(part + proj_b[0])));
    *(float4*)&out[(size_t)n * 16 + l * 4] =
        make_float4(s * v.x, s * v.y, s * v.z, s * v.w);
}

// ---------------------------------------------------------------------------
// One hop + fused DAGNN combine. 16 lanes per node.
// ---------------------------------------------------------------------------
__global__ __launch_bounds__(256) void hop_kernel(
    const float* __restrict__ prev, float* __restrict__ next,
    const int* __restrict__ row_ptr, const int2* __restrict__ csr,
    const float* __restrict__ proj_w, const float* __restrict__ proj_b,
    float* __restrict__ out)
{
    const int t = threadIdx.x;
    const int l = t & 3;
    const int g = (t >> 2) & 3;
    const int n = blockIdx.x * 16 + (t >> 4);
    if (n >= N_NODES) return;
    const int e0 = row_ptr[n], e1 = row_ptr[n + 1];
    float4 acc = make_float4(0.f, 0.f, 0.f, 0.f);
    int e = e0 + g;
    for (; e + 4 < e1; e += 8) {
        int2 ea = csr[e];
        int2 eb = csr[e + 4];
        float  wa = __int_as_float(ea.y);
        float  wb = __int_as_float(eb.y);
        float4 va = *(const float4*)&prev[(size_t)ea.x * 16 + l * 4];
        float4 vb = *(const float4*)&prev[(size_t)eb.x * 16 + l * 4];
        acc.x += wa * va.x; acc.y += wa * va.y; acc.z += wa * va.z; acc.w += wa * va.w;
        acc.x += wb * vb.x; acc.y += wb * vb.y; acc.z += wb * vb.z; acc.w += wb * vb.w;
    }
    if (e < e1) {
        int2 ea = csr[e];
        float  wa = __int_as_float(ea.y);
        float4 va = *(const float4*)&prev[(size_t)ea.x * 16 + l * 4];
        acc.x += wa * va.x; acc.y += wa * va.y; acc.z += wa * va.z; acc.w += wa * va.w;
    }
    acc.x += __shfl_xor(acc.x, 4); acc.y += __shfl_xor(acc.y, 4);
    acc.z += __shfl_xor(acc.z, 4); acc.w += __shfl_xor(acc.w, 4);
    acc.x += __shfl_xor(acc.x, 8); acc.y += __shfl_xor(acc.y, 8);
    acc.z += __shfl_xor(acc.z, 8); acc.w += __shfl_xor(acc.w, 8);

    float4 pw = ((const float4*)proj_w)[l];
    float part = acc.x * pw.x + acc.y * pw.y + acc.z * pw.z + acc.w * pw.w;
    part += __shfl_xor(part, 1);
    part += __shfl_xor(part, 2);
    float s = 1.f / (1.f + __expf(-(part + proj_b[0])));

    if (g == 0) {
        *(float4*)&next[(size_t)n * 16 + l * 4] = acc;
        float4 o = *(float4*)&out[(size_t)n * 16 + l * 4];
        o.x += s * acc.x; o.y += s * acc.y; o.z += s * acc.z; o.w += s * acc.w;
        *(float4*)&out[(size_t)n * 16 + l * 4] = o;
    }
}

// ---------------------------------------------------------------------------
extern "C" void kernel_launch(void* const* d_in, const int* in_sizes, int n_in,
                              void* d_out, int out_size, void* d_ws, size_t ws_size,
                              hipStream_t stream)
{
    const float* x  = (const float*)d_in[0];
    const int*   ei = (const int*)d_in[1];
    const float* ea = (const float*)d_in[2];
    const float* w1 = (const float*)d_in[3];
    const float* b1 = (const float*)d_in[4];
    const float* w2 = (const float*)d_in[5];
    const float* b2 = (const float*)d_in[6];
    const float* w3 = (const float*)d_in[7];
    const float* b3 = (const float*)d_in[8];
    const float* pw = (const float*)d_in[9];
    const float* pb = (const float*)d_in[10];
    float* out = (float*)d_out;

    char* ws = (char*)d_ws;
    size_t off = 0;
    float* hbuf = (float*)(ws + off); off += (size_t)N_NODES * 128 * 4;   // 51.2 MB
    float* ping = (float*)(ws + off); off += (size_t)N_NODES * 16 * 4;    // 6.4 MB
    float* pong = (float*)(ws + off); off += (size_t)N_NODES * 16 * 4;    // 6.4 MB
    int*   rowp = (int*)(ws + off);   off += (((size_t)(N_NODES + 1) * 4) + 15) & ~(size_t)15;
    int*   pcnt = (int*)(ws + off);   off += 256 * 4;
    int*   pbase= (int*)(ws + off);   off += 260 * 4;
    int*   pcur = (int*)(ws + off);   off += 256 * 4;
    int2*  csr  = (int2*)(ws + off);  off += (size_t)E_EDGES * 8;         // 25.6 MB
    // staging (3.2M x 16B = 51.2MB) aliases hbuf: CSR build completes
    // (stream-ordered) before mlp1 writes hbuf.
    int4* staging = (int4*)hbuf;

    const int* src = ei;
    const int* dst = ei + E_EDGES;

    const dim3 blk(256);
    const int nodeGrid16 = (N_NODES + 15) / 16;
    const int nodeGrid64 = (N_NODES + 63) / 64;
    const int chunkGrid  = (E_EDGES + CHUNK - 1) / CHUNK;

    // ---- CSR build: partition multi-split ----
    hipMemsetAsync(pcnt, 0, 256 * 4, stream);
    partition_hist<<<chunkGrid, blk, 0, stream>>>(dst, pcnt);
    partition_scan<<<1, blk, 0, stream>>>(pcnt, pbase, pcur);
    partition_scatter<<<chunkGrid, blk, 0, stream>>>(src, dst, ea, pcur, staging);
    partition_build<<<NPART, blk, 0, stream>>>(staging, pbase, rowp, csr);

    // ---- MLP (overwrites staging/hbuf after CSR build done) ----
    mlp_gemm<256, 128, 8><<<nodeGrid64, blk, 0, stream>>>(x, w1, b1, hbuf);
    mlp_gemm<128, 128, 8><<<nodeGrid64, blk, 0, stream>>>(hbuf, w2, b2, hbuf);
    mlp_gemm<128, 16, 1><<<nodeGrid64, blk, 0, stream>>>(hbuf, w3, b3, ping);

    // ---- k=0 combine term ----
    init_out_kernel<<<nodeGrid64, blk, 0, stream>>>(ping, pw, pb, out);

    // ---- K hops with fused combine ----
    const float* prev = ping;
    float* next = pong;
    for (int k = 0; k < K_HOPS; ++k) {
        hop_kernel<<<nodeGrid16, blk, 0, stream>>>(prev, next, rowp, csr, pw, pb, out);
        float* tmp = (float*)prev; prev = next; next = tmp;
    }
}

// Round 4
// 643.975 us; speedup vs baseline: 2.7496x; 1.3653x over previous
//
#include <hip/hip_runtime.h>
#include <hip/hip_bf16.h>
#include <math.h>

#define N_NODES 100000
#define E_EDGES 3200000
#define K_HOPS  10
#define NPP     512                         // nodes per partition (dst>>9)
#define NPART   ((N_NODES + NPP - 1) / NPP) // 196 partitions
#define CHUNK   8192                        // edges per scatter block
#define EPT     (CHUNK / 256)               // 32 edges per thread

typedef __attribute__((ext_vector_type(8))) short short8;
typedef __attribute__((ext_vector_type(4))) float floatx4;

__device__ __forceinline__ ushort f2bf(float f) {
    uint u = __float_as_uint(f);
    u += 0x7fffu + ((u >> 16) & 1u);
    return (ushort)(u >> 16);
}
__device__ __forceinline__ uint pk2(float a, float b) {
    return (uint)f2bf(a) | ((uint)f2bf(b) << 16);
}
__device__ __forceinline__ float bflo(uint u) { return __uint_as_float(u << 16); }
__device__ __forceinline__ float bfhi(uint u) { return __uint_as_float(u & 0xffff0000u); }

// ---------------------------------------------------------------------------
// MFMA bf16 GEMM: C = relu(A(N x KD) @ W(MD x KD)^T + bias) -> bf16 C.
// A fp32 (converted in-register) or bf16, read directly from global (each
// element consumed once). W staged to LDS as bf16 in 64-wide K slices.
// Block: 256 thr = 4 waves; wave = 32 rows (2 x 16-row tiles) x MD cols.
// ---------------------------------------------------------------------------
template<int KD, int MD, bool A_F32>
__global__ __launch_bounds__(256) void mfma_mlp(
    const void* __restrict__ Av, const float* __restrict__ W,
    const float* __restrict__ bias, ushort* __restrict__ C)
{
    constexpr int NCT = MD / 16;
    constexpr int LDW = 88;                 // ushort stride (176B: 16B-aligned, 2-way banks)
    __shared__ ushort Wl[MD * LDW];

    const int t    = threadIdx.x;
    const int w    = t >> 6;
    const int lane = t & 63;
    const int m    = lane & 15;
    const int quad = lane >> 4;
    const int rowBase = blockIdx.x * 128 + w * 32;

    floatx4 acc[2][NCT];
#pragma unroll
    for (int rt = 0; rt < 2; ++rt)
#pragma unroll
        for (int ct = 0; ct < NCT; ++ct) acc[rt][ct] = (floatx4)0.f;

    for (int kb = 0; kb < KD; kb += 64) {
        // stage W[:, kb:kb+64] as bf16 into LDS
#pragma unroll
        for (int j = 0; j < MD / 16; ++j) {
            int flat = j * 256 + t;
            int n  = flat >> 4;
            int c4 = (flat & 15) * 4;
            floatx4 v = *(const floatx4*)&W[(size_t)n * KD + kb + c4];
            *(uint2*)&Wl[n * LDW + c4] = make_uint2(pk2(v[0], v[1]), pk2(v[2], v[3]));
        }
        __syncthreads();
#pragma unroll
        for (int ks = 0; ks < 64; ks += 32) {
            short8 af[2];
#pragma unroll
            for (int rt = 0; rt < 2; ++rt) {
                int row = rowBase + rt * 16 + m;
                row = row < N_NODES ? row : N_NODES - 1;
                size_t base = (size_t)row * KD + kb + ks + quad * 8;
                if constexpr (A_F32) {
                    const float* ap = (const float*)Av + base;
                    floatx4 a0 = *(const floatx4*)ap;
                    floatx4 a1 = *(const floatx4*)(ap + 4);
                    short8 x;
                    x[0] = (short)f2bf(a0[0]); x[1] = (short)f2bf(a0[1]);
                    x[2] = (short)f2bf(a0[2]); x[3] = (short)f2bf(a0[3]);
                    x[4] = (short)f2bf(a1[0]); x[5] = (short)f2bf(a1[1]);
                    x[6] = (short)f2bf(a1[2]); x[7] = (short)f2bf(a1[3]);
                    af[rt] = x;
                } else {
                    af[rt] = *(const short8*)((const ushort*)Av + base);
                }
            }
#pragma unroll
            for (int ct = 0; ct < NCT; ++ct) {
                short8 bf = *(const short8*)&Wl[(ct * 16 + m) * LDW + ks + quad * 8];
#pragma unroll
                for (int rt = 0; rt < 2; ++rt)
                    acc[rt][ct] = __builtin_amdgcn_mfma_f32_16x16x32_bf16(
                        af[rt], bf, acc[rt][ct], 0, 0, 0);
            }
        }
        __syncthreads();
    }

    // epilogue: bias + relu -> bf16 (D: col=lane&15, row=quad*4+reg)
#pragma unroll
    for (int rt = 0; rt < 2; ++rt) {
#pragma unroll
        for (int r = 0; r < 4; ++r) {
            int row = rowBase + rt * 16 + quad * 4 + r;
            if (row < N_NODES) {
#pragma unroll
                for (int ct = 0; ct < NCT; ++ct) {
                    int col = ct * 16 + m;
                    float v = acc[rt][ct][r] + bias[col];
                    v = v > 0.f ? v : 0.f;
                    C[(size_t)row * MD + col] = f2bf(v);
                }
            }
        }
    }
}

// ---------------------------------------------------------------------------
// CSR build stage A: per-partition histogram (LDS) -> global pcnt
// ---------------------------------------------------------------------------
__global__ __launch_bounds__(256) void partition_hist(
    const int* __restrict__ dst, int* __restrict__ pcnt)
{
    __shared__ int lhist[256];
    const int t = threadIdx.x;
    lhist[t] = 0;
    __syncthreads();
    const int base = blockIdx.x * CHUNK;
#pragma unroll
    for (int j = 0; j < EPT; ++j) {
        int i = base + j * 256 + t;
        if (i < E_EDGES) atomicAdd(&lhist[dst[i] >> 9], 1);
    }
    __syncthreads();
    if (lhist[t] > 0) atomicAdd(&pcnt[t], lhist[t]);
}

// ---------------------------------------------------------------------------
// Stage B: exclusive scan of NPART partition counts (1 block)
// ---------------------------------------------------------------------------
__global__ __launch_bounds__(256) void partition_scan(
    const int* __restrict__ pcnt, int* __restrict__ pbase, int* __restrict__ pcur)
{
    __shared__ int buf[2][256];
    const int t = threadIdx.x;
    int v = (t < NPART) ? pcnt[t] : 0;
    buf[0][t] = v;
    __syncthreads();
    int cur = 0;
#pragma unroll
    for (int d = 1; d < 256; d <<= 1) {
        int x = buf[cur][t];
        if (t >= d) x += buf[cur][t - d];
        buf[cur ^ 1][t] = x;
        cur ^= 1;
        __syncthreads();
    }
    int incl = buf[cur][t];
    int excl = incl - v;
    if (t < NPART) { pbase[t] = excl; pcur[t] = excl; }
    if (t == NPART - 1) pbase[NPART] = incl;
}

// ---------------------------------------------------------------------------
// Stage C: multi-split scatter into partition-major staging (16B entries).
// ---------------------------------------------------------------------------
__global__ __launch_bounds__(256) void partition_scatter(
    const int* __restrict__ src, const int* __restrict__ dst,
    const float* __restrict__ ea, int* __restrict__ pcur,
    int4* __restrict__ staging)
{
    __shared__ int lhist[256];
    __shared__ int lbase[256];
    const int t = threadIdx.x;
    lhist[t] = 0;
    __syncthreads();
    const int base = blockIdx.x * CHUNK;
    int d[EPT];
#pragma unroll
    for (int j = 0; j < EPT; ++j) {
        int i = base + j * 256 + t;
        d[j] = (i < E_EDGES) ? dst[i] : -1;
        if (d[j] >= 0) atomicAdd(&lhist[d[j] >> 9], 1);
    }
    __syncthreads();
    int cnt = lhist[t];
    if (cnt > 0) lbase[t] = atomicAdd(&pcur[t], cnt);
    __syncthreads();
    lhist[t] = 0;
    __syncthreads();
#pragma unroll
    for (int j = 0; j < EPT; ++j) {
        if (d[j] >= 0) {
            int i = base + j * 256 + t;
            int p = d[j] >> 9;
            int r = atomicAdd(&lhist[p], 1);
            staging[lbase[p] + r] = make_int4(src[i], __float_as_int(ea[i]), d[j], 0);
        }
    }
}

// ---------------------------------------------------------------------------
// Stage D: one block per partition -> rowp + final packed CSR.
// ---------------------------------------------------------------------------
__global__ __launch_bounds__(256) void partition_build(
    const int4* __restrict__ staging, const int* __restrict__ pbase,
    int* __restrict__ rowp, int2* __restrict__ csr)
{
    __shared__ int ncnt[NPP];
    __shared__ int wsum[4];
    const int p = blockIdx.x;
    const int t = threadIdx.x;
    const int lane = t & 63, wid = t >> 6;
    const int e0 = pbase[p], e1 = pbase[p + 1];
    const int n0 = p * NPP;

    ncnt[2 * t] = 0; ncnt[2 * t + 1] = 0;
    __syncthreads();
    for (int e = e0 + t; e < e1; e += 256)
        atomicAdd(&ncnt[staging[e].z - n0], 1);
    __syncthreads();

    int a = ncnt[2 * t], b = ncnt[2 * t + 1];
    int pairsum = a + b;
    int x = pairsum;
#pragma unroll
    for (int dd = 1; dd < 64; dd <<= 1) {
        int y = __shfl_up(x, dd);
        if (lane >= dd) x += y;
    }
    if (lane == 63) wsum[wid] = x;
    __syncthreads();
    int wbase = 0;
    for (int ww = 0; ww < 4; ++ww) if (ww < wid) wbase += wsum[ww];
    int excl = wbase + x - pairsum;
    __syncthreads();
    ncnt[2 * t]     = e0 + excl;
    ncnt[2 * t + 1] = e0 + excl + a;
    int nA = n0 + 2 * t, nB = n0 + 2 * t + 1;
    if (nA < N_NODES) rowp[nA] = e0 + excl;
    if (nB < N_NODES) rowp[nB] = e0 + excl + a;
    if (p == NPART - 1 && t == 0) rowp[N_NODES] = E_EDGES;
    __syncthreads();

    for (int e = e0 + t; e < e1; e += 256) {
        int4 en = staging[e];
        int pos = atomicAdd(&ncnt[en.z - n0], 1);
        csr[pos] = make_int2(en.x, en.y);
    }
}

// ---------------------------------------------------------------------------
// k=0 combine: out = sigmoid(h.pw + pb) * h, h in bf16. 2 lanes/node.
// ---------------------------------------------------------------------------
__global__ __launch_bounds__(256) void init_out_bf16(
    const ushort* __restrict__ h, const float* __restrict__ pw,
    const float* __restrict__ pb, float* __restrict__ out)
{
    const int t = threadIdx.x;
    const int l = t & 1;
    const int n = blockIdx.x * 128 + (t >> 1);
    if (n >= N_NODES) return;
    uint4 v = *(const uint4*)&h[(size_t)n * 16 + l * 8];
    float a0 = bflo(v.x), a1 = bfhi(v.x), a2 = bflo(v.y), a3 = bfhi(v.y);
    float a4 = bflo(v.z), a5 = bfhi(v.z), a6 = bflo(v.w), a7 = bfhi(v.w);
    float4 p0 = ((const float4*)pw)[l * 2];
    float4 p1 = ((const float4*)pw)[l * 2 + 1];
    float part = a0 * p0.x + a1 * p0.y + a2 * p0.z + a3 * p0.w
               + a4 * p1.x + a5 * p1.y + a6 * p1.z + a7 * p1.w;
    part += __shfl_xor(part, 1);
    float s = 1.f / (1.f + __expf(-(part + pb[0])));
    *(float4*)&out[(size_t)n * 16 + l * 8]     = make_float4(s*a0, s*a1, s*a2, s*a3);
    *(float4*)&out[(size_t)n * 16 + l * 8 + 4] = make_float4(s*a4, s*a5, s*a6, s*a7);
}

// ---------------------------------------------------------------------------
// One hop (bf16 states) + fused combine. 16 lanes/node:
//   l = t&1 feature half (8 feats), g = (t>>1)&7 edge subgroup.
// ---------------------------------------------------------------------------
__global__ __launch_bounds__(256) void hop_bf16(
    const ushort* __restrict__ prev, ushort* __restrict__ next,
    const int* __restrict__ rowp, const int2* __restrict__ csr,
    const float* __restrict__ pw, const float* __restrict__ pb,
    float* __restrict__ out)
{
    const int t = threadIdx.x;
    const int l = t & 1;
    const int g = (t >> 1) & 7;
    const int n = blockIdx.x * 16 + (t >> 4);
    if (n >= N_NODES) return;
    const int e0 = rowp[n], e1 = rowp[n + 1];
    float a[8];
#pragma unroll
    for (int j = 0; j < 8; ++j) a[j] = 0.f;

    int e = e0 + g;
    for (; e + 8 < e1; e += 16) {
        int2 c0 = csr[e];
        int2 c1 = csr[e + 8];
        float w0 = __int_as_float(c0.y);
        float w1 = __int_as_float(c1.y);
        uint4 v0 = *(const uint4*)&prev[(size_t)c0.x * 16 + l * 8];
        uint4 v1 = *(const uint4*)&prev[(size_t)c1.x * 16 + l * 8];
        a[0] += w0 * bflo(v0.x); a[1] += w0 * bfhi(v0.x);
        a[2] += w0 * bflo(v0.y); a[3] += w0 * bfhi(v0.y);
        a[4] += w0 * bflo(v0.z); a[5] += w0 * bfhi(v0.z);
        a[6] += w0 * bflo(v0.w); a[7] += w0 * bfhi(v0.w);
        a[0] += w1 * bflo(v1.x); a[1] += w1 * bfhi(v1.x);
        a[2] += w1 * bflo(v1.y); a[3] += w1 * bfhi(v1.y);
        a[4] += w1 * bflo(v1.z); a[5] += w1 * bfhi(v1.z);
        a[6] += w1 * bflo(v1.w); a[7] += w1 * bfhi(v1.w);
    }
    if (e < e1) {
        int2 c0 = csr[e];
        float w0 = __int_as_float(c0.y);
        uint4 v0 = *(const uint4*)&prev[(size_t)c0.x * 16 + l * 8];
        a[0] += w0 * bflo(v0.x); a[1] += w0 * bfhi(v0.x);
        a[2] += w0 * bflo(v0.y); a[3] += w0 * bfhi(v0.y);
        a[4] += w0 * bflo(v0.z); a[5] += w0 * bfhi(v0.z);
        a[6] += w0 * bflo(v0.w); a[7] += w0 * bfhi(v0.w);
    }

    // reduce over 8 edge subgroups (lane bits 1..3)
#pragma unroll
    for (int d = 2; d <= 8; d <<= 1) {
#pragma unroll
        for (int j = 0; j < 8; ++j) a[j] += __shfl_xor(a[j], d);
    }

    float4 p0 = ((const float4*)pw)[l * 2];
    float4 p1 = ((const float4*)pw)[l * 2 + 1];
    float part = a[0]*p0.x + a[1]*p0.y + a[2]*p0.z + a[3]*p0.w
               + a[4]*p1.x + a[5]*p1.y + a[6]*p1.z + a[7]*p1.w;
    part += __shfl_xor(part, 1);
    float s = 1.f / (1.f + __expf(-(part + pb[0])));

    if (g == 0) {
        uint4 nv = make_uint4(pk2(a[0], a[1]), pk2(a[2], a[3]),
                              pk2(a[4], a[5]), pk2(a[6], a[7]));
        *(uint4*)&next[(size_t)n * 16 + l * 8] = nv;
        float4 o0 = *(float4*)&out[(size_t)n * 16 + l * 8];
        float4 o1 = *(float4*)&out[(size_t)n * 16 + l * 8 + 4];
        o0.x += s*a[0]; o0.y += s*a[1]; o0.z += s*a[2]; o0.w += s*a[3];
        o1.x += s*a[4]; o1.y += s*a[5]; o1.z += s*a[6]; o1.w += s*a[7];
        *(float4*)&out[(size_t)n * 16 + l * 8]     = o0;
        *(float4*)&out[(size_t)n * 16 + l * 8 + 4] = o1;
    }
}

// ---------------------------------------------------------------------------
extern "C" void kernel_launch(void* const* d_in, const int* in_sizes, int n_in,
                              void* d_out, int out_size, void* d_ws, size_t ws_size,
                              hipStream_t stream)
{
    const float* x  = (const float*)d_in[0];
    const int*   ei = (const int*)d_in[1];
    const float* ea = (const float*)d_in[2];
    const float* w1 = (const float*)d_in[3];
    const float* b1 = (const float*)d_in[4];
    const float* w2 = (const float*)d_in[5];
    const float* b2 = (const float*)d_in[6];
    const float* w3 = (const float*)d_in[7];
    const float* b3 = (const float*)d_in[8];
    const float* pw = (const float*)d_in[9];
    const float* pb = (const float*)d_in[10];
    float* out = (float*)d_out;

    char* ws = (char*)d_ws;
    size_t off = 0;
    char*   region0 = ws + off;           off += (size_t)E_EDGES * 16;   // 51.2 MB
    ushort* pingb = (ushort*)(ws + off);  off += (size_t)N_NODES * 16 * 2; // 3.2 MB
    ushort* pongb = (ushort*)(ws + off);  off += (size_t)N_NODES * 16 * 2; // 3.2 MB
    int*    rowp  = (int*)(ws + off);     off += (((size_t)(N_NODES + 1) * 4) + 15) & ~(size_t)15;
    int*    pcnt  = (int*)(ws + off);     off += 256 * 4;
    int*    pbase = (int*)(ws + off);     off += 260 * 4;
    int*    pcur  = (int*)(ws + off);     off += 256 * 4;
    int2*   csr   = (int2*)(ws + off);    off += (size_t)E_EDGES * 8;    // 25.6 MB

    // staging (51.2MB) aliases h1b/h2b: CSR build completes (stream-ordered)
    // before mlp1 writes h1b.
    int4*   staging = (int4*)region0;
    ushort* h1b = (ushort*)region0;                                  // 25.6 MB
    ushort* h2b = (ushort*)(region0 + (size_t)N_NODES * 128 * 2);    // 25.6 MB

    const int* src = ei;
    const int* dst = ei + E_EDGES;

    const dim3 blk(256);
    const int mlpGrid    = (N_NODES + 127) / 128;   // 782
    const int nodeGrid16 = (N_NODES + 15) / 16;     // 6250
    const int chunkGrid  = (E_EDGES + CHUNK - 1) / CHUNK;

    // ---- CSR build: partition multi-split ----
    hipMemsetAsync(pcnt, 0, 256 * 4, stream);
    partition_hist<<<chunkGrid, blk, 0, stream>>>(dst, pcnt);
    partition_scan<<<1, blk, 0, stream>>>(pcnt, pbase, pcur);
    partition_scatter<<<chunkGrid, blk, 0, stream>>>(src, dst, ea, pcur, staging);
    partition_build<<<NPART, blk, 0, stream>>>(staging, pbase, rowp, csr);

    // ---- MLP via MFMA (bf16) ----
    mfma_mlp<256, 128, true ><<<mlpGrid, blk, 0, stream>>>(x,   w1, b1, h1b);
    mfma_mlp<128, 128, false><<<mlpGrid, blk, 0, stream>>>(h1b, w2, b2, h2b);
    mfma_mlp<128,  16, false><<<mlpGrid, blk, 0, stream>>>(h2b, w3, b3, pingb);

    // ---- k=0 combine term ----
    init_out_bf16<<<mlpGrid, blk, 0, stream>>>(pingb, pw, pb, out);

    // ---- K hops with fused combine ----
    const ushort* prev = pingb;
    ushort* next = pongb;
    for (int k = 0; k < K_HOPS; ++k) {
        hop_bf16<<<nodeGrid16, blk, 0, stream>>>(prev, next, rowp, csr, pw, pb, out);
        ushort* tmp = (ushort*)prev; prev = next; next = tmp;
    }
}

// Round 5
// 640.245 us; speedup vs baseline: 2.7656x; 1.0058x over previous
//
#include <hip/hip_runtime.h>
#include <hip/hip_bf16.h>
#include <math.h>

#define N_NODES 100000
#define E_EDGES 3200000
#define K_HOPS  10
#define NPP     256                          // nodes per partition (dst>>8)
#define NPART   ((N_NODES + NPP - 1) / NPP)  // 391 partitions
#define CHUNK   4096                         // edges per scatter block
#define EPT     (CHUNK / 256)                // 16 edges per thread
#define NCHUNK  ((E_EDGES + CHUNK - 1) / CHUNK)   // 782 chunks
#define NFLAT   (NPART * NCHUNK)                  // 305762
#define SSEG    8192
#define GA      ((NFLAT + SSEG - 1) / SSEG)       // 38 scan blocks

typedef __attribute__((ext_vector_type(8))) short short8;
typedef __attribute__((ext_vector_type(4))) float floatx4;

__device__ __forceinline__ ushort f2bf(float f) {
    uint u = __float_as_uint(f);
    u += 0x7fffu + ((u >> 16) & 1u);
    return (ushort)(u >> 16);
}
__device__ __forceinline__ uint pk2(float a, float b) {
    return (uint)f2bf(a) | ((uint)f2bf(b) << 16);
}
__device__ __forceinline__ float bflo(uint u) { return __uint_as_float(u << 16); }
__device__ __forceinline__ float bfhi(uint u) { return __uint_as_float(u & 0xffff0000u); }

// ---------------------------------------------------------------------------
// MFMA bf16 GEMM: C = relu(A(N x KD) @ W(MD x KD)^T + bias) -> bf16 C.
// ---------------------------------------------------------------------------
template<int KD, int MD, bool A_F32>
__global__ __launch_bounds__(256) void mfma_mlp(
    const void* __restrict__ Av, const float* __restrict__ W,
    const float* __restrict__ bias, ushort* __restrict__ C)
{
    constexpr int NCT = MD / 16;
    constexpr int LDW = 88;
    __shared__ ushort Wl[MD * LDW];

    const int t    = threadIdx.x;
    const int w    = t >> 6;
    const int lane = t & 63;
    const int m    = lane & 15;
    const int quad = lane >> 4;
    const int rowBase = blockIdx.x * 128 + w * 32;

    floatx4 acc[2][NCT];
#pragma unroll
    for (int rt = 0; rt < 2; ++rt)
#pragma unroll
        for (int ct = 0; ct < NCT; ++ct) acc[rt][ct] = (floatx4)0.f;

    for (int kb = 0; kb < KD; kb += 64) {
#pragma unroll
        for (int j = 0; j < MD / 16; ++j) {
            int flat = j * 256 + t;
            int n  = flat >> 4;
            int c4 = (flat & 15) * 4;
            floatx4 v = *(const floatx4*)&W[(size_t)n * KD + kb + c4];
            *(uint2*)&Wl[n * LDW + c4] = make_uint2(pk2(v[0], v[1]), pk2(v[2], v[3]));
        }
        __syncthreads();
#pragma unroll
        for (int ks = 0; ks < 64; ks += 32) {
            short8 af[2];
#pragma unroll
            for (int rt = 0; rt < 2; ++rt) {
                int row = rowBase + rt * 16 + m;
                row = row < N_NODES ? row : N_NODES - 1;
                size_t base = (size_t)row * KD + kb + ks + quad * 8;
                if constexpr (A_F32) {
                    const float* ap = (const float*)Av + base;
                    floatx4 a0 = *(const floatx4*)ap;
                    floatx4 a1 = *(const floatx4*)(ap + 4);
                    short8 x;
                    x[0] = (short)f2bf(a0[0]); x[1] = (short)f2bf(a0[1]);
                    x[2] = (short)f2bf(a0[2]); x[3] = (short)f2bf(a0[3]);
                    x[4] = (short)f2bf(a1[0]); x[5] = (short)f2bf(a1[1]);
                    x[6] = (short)f2bf(a1[2]); x[7] = (short)f2bf(a1[3]);
                    af[rt] = x;
                } else {
                    af[rt] = *(const short8*)((const ushort*)Av + base);
                }
            }
#pragma unroll
            for (int ct = 0; ct < NCT; ++ct) {
                short8 bf = *(const short8*)&Wl[(ct * 16 + m) * LDW + ks + quad * 8];
#pragma unroll
                for (int rt = 0; rt < 2; ++rt)
                    acc[rt][ct] = __builtin_amdgcn_mfma_f32_16x16x32_bf16(
                        af[rt], bf, acc[rt][ct], 0, 0, 0);
            }
        }
        __syncthreads();
    }

#pragma unroll
    for (int rt = 0; rt < 2; ++rt) {
#pragma unroll
        for (int r = 0; r < 4; ++r) {
            int row = rowBase + rt * 16 + quad * 4 + r;
            if (row < N_NODES) {
#pragma unroll
                for (int ct = 0; ct < NCT; ++ct) {
                    int col = ct * 16 + m;
                    float v = acc[rt][ct][r] + bias[col];
                    v = v > 0.f ? v : 0.f;
                    C[(size_t)row * MD + col] = f2bf(v);
                }
            }
        }
    }
}

// ---------------------------------------------------------------------------
// CSR stage 1: per-chunk per-partition histogram -> cmat[p*NCHUNK + chunk]
// ---------------------------------------------------------------------------
__global__ __launch_bounds__(256) void hist2(
    const int* __restrict__ dst, int* __restrict__ cmat)
{
    __shared__ int lhist[NPART];
    const int t = threadIdx.x;
    for (int p = t; p < NPART; p += 256) lhist[p] = 0;
    __syncthreads();
    const int base = blockIdx.x * CHUNK;
#pragma unroll
    for (int j = 0; j < EPT; ++j) {
        int i = base + j * 256 + t;
        if (i < E_EDGES) atomicAdd(&lhist[dst[i] >> 8], 1);
    }
    __syncthreads();
    for (int p = t; p < NPART; p += 256)
        cmat[p * NCHUNK + blockIdx.x] = lhist[p];
}

// ---------------------------------------------------------------------------
// Scan level A: per-8192-segment reduction -> bsum
// ---------------------------------------------------------------------------
__global__ __launch_bounds__(1024) void scan_reduce(
    const int* __restrict__ cmat, int* __restrict__ bsum)
{
    __shared__ int wsum[16];
    const int t = threadIdx.x, lane = t & 63, wid = t >> 6;
    int base = blockIdx.x * SSEG + t * 8;
    int s = 0;
#pragma unroll
    for (int j = 0; j < 8; ++j) {
        int idx = base + j;
        if (idx < NFLAT) s += cmat[idx];
    }
#pragma unroll
    for (int d = 1; d < 64; d <<= 1) s += __shfl_xor(s, d);
    if (lane == 0) wsum[wid] = s;
    __syncthreads();
    if (t == 0) {
        int tot = 0;
#pragma unroll
        for (int i = 0; i < 16; ++i) tot += wsum[i];
        bsum[blockIdx.x] = tot;
    }
}

// ---------------------------------------------------------------------------
// Scan level B: exclusive scan of GA block sums (single wave)
// ---------------------------------------------------------------------------
__global__ void scan_tops(const int* __restrict__ bsum, int* __restrict__ boff)
{
    const int t = threadIdx.x;
    int v = (t < GA) ? bsum[t] : 0;
    int x = v;
#pragma unroll
    for (int d = 1; d < 64; d <<= 1) {
        int y = __shfl_up(x, d);
        if (t >= d) x += y;
    }
    if (t < GA) boff[t] = x - v;
}

// ---------------------------------------------------------------------------
// Scan level C: full exclusive scan applied in-place; also emits pbase[].
// ---------------------------------------------------------------------------
__global__ __launch_bounds__(1024) void scan_apply(
    int* __restrict__ cmat, const int* __restrict__ boff, int* __restrict__ pbase)
{
    __shared__ int wsum[16];
    __shared__ int woff[17];
    const int t = threadIdx.x, lane = t & 63, wid = t >> 6;
    int base = blockIdx.x * SSEG + t * 8;
    int v[8], pre[8];
    int s = 0;
#pragma unroll
    for (int j = 0; j < 8; ++j) {
        int idx = base + j;
        v[j] = (idx < NFLAT) ? cmat[idx] : 0;
        pre[j] = s;
        s += v[j];
    }
    int x = s;
#pragma unroll
    for (int d = 1; d < 64; d <<= 1) {
        int y = __shfl_up(x, d);
        if (lane >= d) x += y;
    }
    if (lane == 63) wsum[wid] = x;
    __syncthreads();
    if (wid == 0) {
        int w = (lane < 16) ? wsum[lane] : 0;
#pragma unroll
        for (int d = 1; d < 16; d <<= 1) {
            int y = __shfl_up(w, d);
            if (lane >= d) w += y;
        }
        if (lane < 16) woff[lane + 1] = w;
        if (lane == 0) woff[0] = 0;
    }
    __syncthreads();
    int tbase = boff[blockIdx.x] + woff[wid] + (x - s);
#pragma unroll
    for (int j = 0; j < 8; ++j) {
        int idx = base + j;
        if (idx < NFLAT) {
            int e = tbase + pre[j];
            cmat[idx] = e;
            if (idx % NCHUNK == 0) pbase[idx / NCHUNK] = e;
        }
    }
    if (blockIdx.x == 0 && t == 0) pbase[NPART] = E_EDGES;
}

// ---------------------------------------------------------------------------
// CSR stage 2: contention-free scatter. Each block loads its 391 absolute
// bases into LDS, ranks edges with LDS atomics, writes 16B staged entries.
// ---------------------------------------------------------------------------
__global__ __launch_bounds__(256) void scatter2(
    const int* __restrict__ src, const int* __restrict__ dst,
    const float* __restrict__ ea, const int* __restrict__ cbase,
    int4* __restrict__ staging)
{
    __shared__ int lcur[NPART];
    const int t = threadIdx.x;
    const int b = blockIdx.x;
    for (int p = t; p < NPART; p += 256) lcur[p] = cbase[p * NCHUNK + b];
    __syncthreads();
    const int base = b * CHUNK;
#pragma unroll
    for (int j = 0; j < EPT; ++j) {
        int i = base + j * 256 + t;
        if (i < E_EDGES) {
            int d = dst[i];
            int pos = atomicAdd(&lcur[d >> 8], 1);
            staging[pos] = make_int4(src[i], __float_as_int(ea[i]), d, 0);
        }
    }
}

// ---------------------------------------------------------------------------
// CSR stage 3: one 1024-thread block per partition -> rowp + final CSR.
// ---------------------------------------------------------------------------
__global__ __launch_bounds__(1024) void partition_build(
    const int4* __restrict__ staging, const int* __restrict__ pbase,
    int* __restrict__ rowp, int2* __restrict__ csr)
{
    __shared__ int ncnt[NPP];
    __shared__ int wsum[4];
    const int p = blockIdx.x;
    const int t = threadIdx.x;
    const int e0 = pbase[p], e1 = pbase[p + 1];
    const int cnt = e1 - e0;
    const int n0 = p << 8;

    if (t < NPP) ncnt[t] = 0;
    __syncthreads();
    for (int e = t; e < cnt; e += 1024)
        atomicAdd(&ncnt[staging[e0 + e].z - n0], 1);
    __syncthreads();

    int x = 0, v = 0;
    if (t < NPP) {
        const int lane = t & 63, wid = t >> 6;
        v = ncnt[t];
        x = v;
#pragma unroll
        for (int d = 1; d < 64; d <<= 1) {
            int y = __shfl_up(x, d);
            if (lane >= d) x += y;
        }
        if (lane == 63) wsum[wid] = x;
    }
    __syncthreads();
    if (t < NPP) {
        const int wid = t >> 6;
        int wbase = 0;
#pragma unroll
        for (int w = 0; w < 4; ++w) if (w < wid) wbase += wsum[w];
        int excl = wbase + x - v;
        ncnt[t] = e0 + excl;
        int n = n0 + t;
        if (n < N_NODES) rowp[n] = e0 + excl;
    }
    if (p == NPART - 1 && t == 0) rowp[N_NODES] = E_EDGES;
    __syncthreads();

    for (int e = t; e < cnt; e += 1024) {
        int4 en = staging[e0 + e];
        int pos = atomicAdd(&ncnt[en.z - n0], 1);
        csr[pos] = make_int2(en.x, en.y);
    }
}

// ---------------------------------------------------------------------------
// k=0 combine: out = sigmoid(h.pw + pb) * h, h in bf16. 2 lanes/node.
// ---------------------------------------------------------------------------
__global__ __launch_bounds__(256) void init_out_bf16(
    const ushort* __restrict__ h, const float* __restrict__ pw,
    const float* __restrict__ pb, float* __restrict__ out)
{
    const int t = threadIdx.x;
    const int l = t & 1;
    const int n = blockIdx.x * 128 + (t >> 1);
    if (n >= N_NODES) return;
    uint4 v = *(const uint4*)&h[(size_t)n * 16 + l * 8];
    float a0 = bflo(v.x), a1 = bfhi(v.x), a2 = bflo(v.y), a3 = bfhi(v.y);
    float a4 = bflo(v.z), a5 = bfhi(v.z), a6 = bflo(v.w), a7 = bfhi(v.w);
    float4 p0 = ((const float4*)pw)[l * 2];
    float4 p1 = ((const float4*)pw)[l * 2 + 1];
    float part = a0 * p0.x + a1 * p0.y + a2 * p0.z + a3 * p0.w
               + a4 * p1.x + a5 * p1.y + a6 * p1.z + a7 * p1.w;
    part += __shfl_xor(part, 1);
    float s = 1.f / (1.f + __expf(-(part + pb[0])));
    *(float4*)&out[(size_t)n * 16 + l * 8]     = make_float4(s*a0, s*a1, s*a2, s*a3);
    *(float4*)&out[(size_t)n * 16 + l * 8 + 4] = make_float4(s*a4, s*a5, s*a6, s*a7);
}

// ---------------------------------------------------------------------------
// One hop (bf16 states) + fused combine. 8 lanes/node:
//   l = t&1 feature half, g = (t>>1)&3 edge subgroup.
// ---------------------------------------------------------------------------
__global__ __launch_bounds__(256) void hop_bf16(
    const ushort* __restrict__ prev, ushort* __restrict__ next,
    const int* __restrict__ rowp, const int2* __restrict__ csr,
    const float* __restrict__ pw, const float* __restrict__ pb,
    float* __restrict__ out)
{
    const int t = threadIdx.x;
    const int l = t & 1;
    const int g = (t >> 1) & 3;
    const int n = blockIdx.x * 32 + (t >> 3);
    if (n >= N_NODES) return;
    const int e0 = rowp[n], e1 = rowp[n + 1];
    float a[8];
#pragma unroll
    for (int j = 0; j < 8; ++j) a[j] = 0.f;

    int e = e0 + g;
    for (; e + 4 < e1; e += 8) {
        int2 c0 = csr[e];
        int2 c1 = csr[e + 4];
        float w0 = __int_as_float(c0.y);
        float w1 = __int_as_float(c1.y);
        uint4 v0 = *(const uint4*)&prev[(size_t)c0.x * 16 + l * 8];
        uint4 v1 = *(const uint4*)&prev[(size_t)c1.x * 16 + l * 8];
        a[0] += w0 * bflo(v0.x); a[1] += w0 * bfhi(v0.x);
        a[2] += w0 * bflo(v0.y); a[3] += w0 * bfhi(v0.y);
        a[4] += w0 * bflo(v0.z); a[5] += w0 * bfhi(v0.z);
        a[6] += w0 * bflo(v0.w); a[7] += w0 * bfhi(v0.w);
        a[0] += w1 * bflo(v1.x); a[1] += w1 * bfhi(v1.x);
        a[2] += w1 * bflo(v1.y); a[3] += w1 * bfhi(v1.y);
        a[4] += w1 * bflo(v1.z); a[5] += w1 * bfhi(v1.z);
        a[6] += w1 * bflo(v1.w); a[7] += w1 * bfhi(v1.w);
    }
    if (e < e1) {
        int2 c0 = csr[e];
        float w0 = __int_as_float(c0.y);
        uint4 v0 = *(const uint4*)&prev[(size_t)c0.x * 16 + l * 8];
        a[0] += w0 * bflo(v0.x); a[1] += w0 * bfhi(v0.x);
        a[2] += w0 * bflo(v0.y); a[3] += w0 * bfhi(v0.y);
        a[4] += w0 * bflo(v0.z); a[5] += w0 * bfhi(v0.z);
        a[6] += w0 * bflo(v0.w); a[7] += w0 * bfhi(v0.w);
    }

    // reduce over 4 edge subgroups (lane bits 1..2)
#pragma unroll
    for (int d = 2; d <= 4; d <<= 1) {
#pragma unroll
        for (int j = 0; j < 8; ++j) a[j] += __shfl_xor(a[j], d);
    }

    float4 p0 = ((const float4*)pw)[l * 2];
    float4 p1 = ((const float4*)pw)[l * 2 + 1];
    float part = a[0]*p0.x + a[1]*p0.y + a[2]*p0.z + a[3]*p0.w
               + a[4]*p1.x + a[5]*p1.y + a[6]*p1.z + a[7]*p1.w;
    part += __shfl_xor(part, 1);
    float s = 1.f / (1.f + __expf(-(part + pb[0])));

    if (g == 0) {
        uint4 nv = make_uint4(pk2(a[0], a[1]), pk2(a[2], a[3]),
                              pk2(a[4], a[5]), pk2(a[6], a[7]));
        *(uint4*)&next[(size_t)n * 16 + l * 8] = nv;
        float4 o0 = *(float4*)&out[(size_t)n * 16 + l * 8];
        float4 o1 = *(float4*)&out[(size_t)n * 16 + l * 8 + 4];
        o0.x += s*a[0]; o0.y += s*a[1]; o0.z += s*a[2]; o0.w += s*a[3];
        o1.x += s*a[4]; o1.y += s*a[5]; o1.z += s*a[6]; o1.w += s*a[7];
        *(float4*)&out[(size_t)n * 16 + l * 8]     = o0;
        *(float4*)&out[(size_t)n * 16 + l * 8 + 4] = o1;
    }
}

// ---------------------------------------------------------------------------
extern "C" void kernel_launch(void* const* d_in, const int* in_sizes, int n_in,
                              void* d_out, int out_size, void* d_ws, size_t ws_size,
                              hipStream_t stream)
{
    const float* x  = (const float*)d_in[0];
    const int*   ei = (const int*)d_in[1];
    const float* ea = (const float*)d_in[2];
    const float* w1 = (const float*)d_in[3];
    const float* b1 = (const float*)d_in[4];
    const float* w2 = (const float*)d_in[5];
    const float* b2 = (const float*)d_in[6];
    const float* w3 = (const float*)d_in[7];
    const float* b3 = (const float*)d_in[8];
    const float* pw = (const float*)d_in[9];
    const float* pb = (const float*)d_in[10];
    float* out = (float*)d_out;

    char* ws = (char*)d_ws;
    size_t off = 0;
    char*   region0 = ws + off;           off += (size_t)E_EDGES * 16;       // 51.2 MB
    ushort* pingb = (ushort*)(ws + off);  off += (size_t)N_NODES * 16 * 2;   // 3.2 MB
    ushort* pongb = (ushort*)(ws + off);  off += (size_t)N_NODES * 16 * 2;   // 3.2 MB
    int*    rowp  = (int*)(ws + off);     off += (((size_t)(N_NODES + 1) * 4) + 15) & ~(size_t)15;
    int*    cmat  = (int*)(ws + off);     off += ((size_t)NFLAT * 4 + 15) & ~(size_t)15;  // 1.22 MB
    int*    bsum  = (int*)(ws + off);     off += ((size_t)GA * 4 + 15) & ~(size_t)15;
    int*    boff  = (int*)(ws + off);     off += ((size_t)GA * 4 + 15) & ~(size_t)15;
    int*    pbase = (int*)(ws + off);     off += ((size_t)(NPART + 1) * 4 + 15) & ~(size_t)15;
    int2*   csr   = (int2*)(ws + off);    off += (size_t)E_EDGES * 8;        // 25.6 MB

    // staging (51.2MB) aliases h1b/h2b: CSR build completes (stream-ordered)
    // before mlp1 writes h1b.
    int4*   staging = (int4*)region0;
    ushort* h1b = (ushort*)region0;                                  // 25.6 MB
    ushort* h2b = (ushort*)(region0 + (size_t)N_NODES * 128 * 2);    // 25.6 MB

    const int* src = ei;
    const int* dst = ei + E_EDGES;

    const dim3 blk(256);
    const int mlpGrid    = (N_NODES + 127) / 128;   // 782
    const int hopGrid    = (N_NODES + 31) / 32;     // 3125

    // ---- CSR build: contention-free multi-split ----
    hist2<<<NCHUNK, blk, 0, stream>>>(dst, cmat);
    scan_reduce<<<GA, 1024, 0, stream>>>(cmat, bsum);
    scan_tops<<<1, 64, 0, stream>>>(bsum, boff);
    scan_apply<<<GA, 1024, 0, stream>>>(cmat, boff, pbase);
    scatter2<<<NCHUNK, blk, 0, stream>>>(src, dst, ea, cmat, staging);
    partition_build<<<NPART, 1024, 0, stream>>>(staging, pbase, rowp, csr);

    // ---- MLP via MFMA (bf16) ----
    mfma_mlp<256, 128, true ><<<mlpGrid, blk, 0, stream>>>(x,   w1, b1, h1b);
    mfma_mlp<128, 128, false><<<mlpGrid, blk, 0, stream>>>(h1b, w2, b2, h2b);
    mfma_mlp<128,  16, false><<<mlpGrid, blk, 0, stream>>>(h2b, w3, b3, pingb);

    // ---- k=0 combine term ----
    init_out_bf16<<<mlpGrid, blk, 0, stream>>>(pingb, pw, pb, out);

    // ---- K hops with fused combine ----
    const ushort* prev = pingb;
    ushort* next = pongb;
    for (int k = 0; k < K_HOPS; ++k) {
        hop_bf16<<<hopGrid, blk, 0, stream>>>(prev, next, rowp, csr, pw, pb, out);
        ushort* tmp = (ushort*)prev; prev = next; next = tmp;
    }
}